// Round 13
// baseline (537.271 us; speedup 1.0000x reference)
//
#include <hip/hip_runtime.h>
#include <math.h>

// CTC prefix beam search — fused single dispatch.
//  blocks 1..T: per-frame log-softmax + stable top-10 + 32-entry symbol->logp
//               LUT (sentinel=+inf if not in top-10) -> d_ws.
//  block 0 (2 waves): one candidate per lane (110); lanes 110-119 rank-shadow
//  the g1 keys. Winners prefetch next frame's lut[nlast] at COMMIT time.
//  Frame records staged into LDS just-in-time in 32-frame chunks (wave0),
//  overlapping producer completion with the scan. 2 barriers/step.

#define BB 10
#define KK 10
#define VV 29
#define TMAX 256
#define FS 56                 // floats per frame record
#define NEGF (-1e30f)
#define DUPF (-2e30f)
#define MAGICF 0x5CA7F00Du
#define SENTB 0x7F800000      // +inf bits: "symbol not in top-10"

__device__ __forceinline__ float lae(float a, float b) {
    float m = fmaxf(a, b);
    return m + log1pf(expf(fminf(a, b) - m));
}
__device__ __forceinline__ unsigned int ordf(float f) {
    unsigned int u = __float_as_uint(f);
    return (u & 0x80000000u) ? ~u : (u | 0x80000000u);
}

// frame record (56 floats): [0..19] (sym_bits,p)*10 ; [20] blank_slot_bits ;
// [21] p_blank ; [22..23] pad ; [24..55] lut[32]
__device__ __forceinline__ void topk_frame(const float* __restrict__ logits,
                                           int blank, int t, float* __restrict__ o,
                                           int L) {
    float lp = (L < VV) ? logits[t * VV + L] : -INFINITY;
    float mx = lp;
    #pragma unroll
    for (int off = 32; off >= 1; off >>= 1) mx = fmaxf(mx, __shfl_xor(mx, off));
    float sm = (L < VV) ? expf(lp - mx) : 0.f;
    #pragma unroll
    for (int off = 32; off >= 1; off >>= 1) sm += __shfl_xor(sm, off);
    float lz = mx + logf(sm);
    int arank = 0;
    #pragma unroll
    for (int u = 0; u < VV; ++u) {
        float lu = __shfl(lp, u);
        arank += (lu > lp) || (lu == lp && u < L);   // tie -> lower index
    }
    bool win = (L < VV) && (arank < KK);
    if (win) { o[2 * arank] = __int_as_float(L); o[2 * arank + 1] = lp - lz; }
    if (L < 32) o[24 + L] = win ? (lp - lz) : __int_as_float(SENTB);
    unsigned long long bm = __ballot(win && (L == blank));
    if (bm) { if (L == blank) { o[20] = __int_as_float(arank); o[21] = lp - lz; } }
    else    { if (L == 0)     { o[20] = __int_as_float(-1);    o[21] = 0.f;     } }
}

__global__ __launch_bounds__(128) void fused_kernel(
        const float* __restrict__ logits, const int* __restrict__ blank_p,
        float* __restrict__ out, int T, float* __restrict__ tkbuf,
        unsigned int* fflags) {

    const int L = threadIdx.x;

    if (blockIdx.x != 0) {
        const int t = blockIdx.x - 1;
        if (L < 64) topk_frame(logits, blank_p[0], t, tkbuf + t * FS, L);
        __syncthreads();
        if (L == 0)
            __hip_atomic_store(&fflags[t], MAGICF, __ATOMIC_RELEASE,
                               __HIP_MEMORY_SCOPE_AGENT);
        return;
    }

    // ========================= scan block (2 waves) =========================
    __shared__ __align__(16) float tkl[TMAX * FS];
    __shared__ __align__(16) float bsrow[16][8];  // {pb,pnb,f2,len, ppb,ppnb,pkl,_}
    __shared__ __align__(16) int   dupsig[12];    // (last+16) | (par+1)<<8
    __shared__ __align__(16) unsigned long long kbuf[128];
    __shared__ __align__(16) float4 aux4[12];     // {pay_pb,pay_pnb,nlast+16,_}
    __shared__ unsigned short hist[TMAX][BB];
    __shared__ signed char pout[BB][TMAX];

    if (L < BB) {
        int last0 = (L == 0) ? -1 : -(L + 2);     // empty=slot0, sentinels 1..9
        int par0  = (L == 0) ? -1 : 0;
        int f2 = (last0 + 16) | ((par0 + 1) << 8) | ((-1 + 16) << 16);
        *(float4*)&bsrow[L][0] = make_float4((L == 0) ? 0.f : NEGF, NEGF,
                                             __int_as_float(f2), __int_as_float(0));
        // parent payload = empty beam; own pkl = sentinel (no valid last at t=0)
        *(float4*)&bsrow[L][4] = make_float4(0.f, NEGF, __int_as_float(SENTB), 0.f);
        dupsig[L] = f2 & 0xFFFF;
    } else if (L < 12) dupsig[L] = 0;

    // ---- upfront: stage chunks 0 and 1 (frames 0..63) as soon as ready
    if (L < 64) {
        for (;;) {
            int idx = L;
            unsigned f = (idx < T)
                ? __hip_atomic_load(&fflags[idx], __ATOMIC_RELAXED,
                                    __HIP_MEMORY_SCOPE_AGENT)
                : MAGICF;
            if (__all(f == MAGICF)) break;
        }
        __builtin_amdgcn_fence(__ATOMIC_ACQUIRE, "agent");
        int nf = (T < 64) ? T : 64;
        int n4 = (nf * FS) >> 2;                  // FS=56 -> 14 float4 per frame
        const float4* g4 = (const float4*)tkbuf;
        float4* l4 = (float4*)tkl;
        for (int i = L; i < n4; i += 64) l4[i] = g4[i];
    }
    __syncthreads();

    // roles: L<10 real g1 (c=L); 10..109 g2 (c=L); 110..119 rank-shadow; rest idle
    const int c = L;
    const bool active = c < BB + BB * KK;         // 110
    const bool isg1 = c < BB;
    const bool isshadow = (L >= 110 && L < 120);
    const int b = isg1 ? c : (c - 10) / 10;
    const int k = isg1 ? 0 : (c - 10) % 10;
    const int ofs = isg1 ? 20 : 2 * k;            // uniform per-lane frame offset
    const int blank = blank_p[0];

    float2 fpr = *(const float2*)&tkl[ofs];       // frame t=0 data for this lane

    for (int t = 0; t < T; ++t) {
        // ---- JIT staging: every 32nd step, wave0 stages chunk (t/32)+2.
        // First use is >=31 barrier-separated steps later.
        if ((t & 31) == 0 && L < 64) {
            int f0 = ((t >> 5) + 2) << 5;
            if (f0 < T) {
                int nf = (T - f0 < 32) ? (T - f0) : 32;
                for (;;) {
                    unsigned f = (L < nf)
                        ? __hip_atomic_load(&fflags[f0 + L], __ATOMIC_RELAXED,
                                            __HIP_MEMORY_SCOPE_AGENT)
                        : MAGICF;
                    if (__all(f == MAGICF)) break;
                }
                __builtin_amdgcn_fence(__ATOMIC_ACQUIRE, "agent");
                int n4 = (nf * FS) >> 2;
                const float4* g4 = (const float4*)(tkbuf + f0 * FS);
                float4* l4 = (float4*)(tkl + f0 * FS);
                for (int i = L; i < n4; i += 64) l4[i] = g4[i];
            }
        }

        // ---- P1: candidate scores (state reads ordered by prev end barrier)
        float tot = -INFINITY, pay_pb = NEGF, pay_pnb = NEGF;
        int nlen = 0, nlast = 0, xsl = -1, tok = -1;

        if (active) {
            float4 rowA = *(const float4*)&bsrow[b][0];
            int f2 = __float_as_int(rowA.z);
            int last_b = (f2 & 255) - 16;
            if (isg1) {
                float4 rowB = *(const float4*)&bsrow[b][4];   // {ppb,ppnb,pkl,_}
                int par_b  = ((f2 >> 8) & 255) - 1;
                int last_p = ((f2 >> 16) & 255) - 16;
                nlen = __float_as_int(rowA.w);
                nlast = last_b; xsl = par_b; tok = -1;
                int bk = __float_as_int(fpr.x);               // blank slot or -1
                float pbl = fpr.y;
                float pkl = rowB.z;
                if (bk >= 0) pay_pb = lae(rowA.x + pbl, rowA.y + pbl);
                if (__float_as_int(rowB.z) != SENTB) {
                    float a = rowA.y + pkl;                   // g1 member (lower idx)
                    if (par_b >= 0) {
                        float e = (last_b == last_p) ? (rowB.x + pkl)
                                   : lae(rowB.x + pkl, rowB.y + pkl);
                        float mxx = fmaxf(a, e);
                        pay_pnb = mxx + logf(expf(a - mxx) + expf(e - mxx));
                    } else pay_pnb = a;
                }
                tot = lae(pay_pb, pay_pnb);
            } else {
                int s = __float_as_int(fpr.x); float p = fpr.y;
                nlen = __float_as_int(rowA.w) + 1;
                nlast = s; xsl = b; tok = s;
                int4 dg0 = *(const int4*)&dupsig[0];
                int4 dg1 = *(const int4*)&dupsig[4];
                int2 dg2 = *(const int2*)&dupsig[8];
                int sig[BB] = {dg0.x, dg0.y, dg0.z, dg0.w,
                               dg1.x, dg1.y, dg1.z, dg1.w, dg2.x, dg2.y};
                int target = ((b + 1) << 8) | (s + 16);
                bool dup = false;
                #pragma unroll
                for (int i = 0; i < BB; ++i) dup = dup || (sig[i] == target);
                float v;
                if (s == blank)        v = NEGF;
                else if (s == last_b)  v = rowA.x + p;
                else                   v = lae(rowA.x + p, rowA.y + p);
                pay_pnb = v;
                tot = dup ? DUPF : v;        // lae(NEGF,v) == v bitwise in f32
            }
        }

        unsigned long long key =
            (((unsigned long long)ordf(tot)) << 32) | (unsigned)(127 - c);
        if (active) kbuf[c] = key;
        if (isg1)   aux4[c] = make_float4(pay_pb, pay_pnb,
                                          __int_as_float(nlast + 16), 0.f);
        __syncthreads();                                   // B1: keys+aux visible

        // shadow lanes adopt the g1 key they will rank (issued first post-B1)
        if (isshadow) key = kbuf[L - 110];

        // prefetch next frame's per-lane float2 (hidden under rank)
        int tn = (t + 1 < T) ? (t + 1) : t;
        fpr = *(const float2*)&tkl[tn * FS + ofs];

        // ---- exact rank (value desc, index asc) vs all 110 keys (wave-uniform)
        int r = 0;
        const ulonglong2* k2 = (const ulonglong2*)kbuf;
        #pragma unroll
        for (int q = 0; q < 55; ++q) {
            ulonglong2 w = k2[q];
            r += (w.x > key) + (w.y > key);
        }

        // parent new-slot via intra-wave shuffle:
        // wave0 sources = real g1 lanes 0-9; wave1 sources = shadow 46-55 (rel).
        int g1r_val = ((isg1 || isshadow) && r < BB) ? r : -1;
        int xs = (xsl < 0) ? 0 : xsl;
        int src = (L < 64) ? xs : (46 + xs);
        int g1r_sh = __shfl(g1r_val, src);

        // ---- full commit (winners only; ranks unique)
        if (active && r < BB) {
            float4 ax = aux4[xs];          // parent payload (pre-B1 publish)
            int npar, plast16; float ppb, ppnb;
            if (xsl >= 0) {
                npar = g1r_sh; plast16 = __float_as_int(ax.z);
                ppb = ax.x; ppnb = ax.y;
            } else { npar = -1; plast16 = 15; ppb = 0.f; ppnb = NEGF; }
            // prefetch next frame's lut[nlast] for own g1 next step
            int li = ((unsigned)nlast < VV) ? nlast : 29;   // 29..31 = sentinel
            float npkl = tkl[tn * FS + 24 + li];
            int f2n = (nlast + 16) | ((npar + 1) << 8) | (plast16 << 16);
            *(float4*)&bsrow[r][0] = make_float4(isg1 ? pay_pb : NEGF, pay_pnb,
                                                 __int_as_float(f2n),
                                                 __int_as_float(nlen));
            *(float4*)&bsrow[r][4] = make_float4(ppb, ppnb, npkl, 0.f);
            dupsig[r] = f2n & 0xFFFF;
            hist[t][r] = (unsigned short)(b | ((tok + 1) << 8));
        }
        __syncthreads();                                   // B2: state committed
    }

    // ---- outputs: [scores(B) | prefixes(B*T) | lengths(B)] as f32
    int mylen = 0;
    if (L < BB) {
        float4 rj = *(const float4*)&bsrow[L][0];
        mylen = __float_as_int(rj.w);
        out[L] = lae(rj.x, rj.y);
        out[BB + BB * T + L] = (float)mylen;
    }
    for (int i = L; i < BB * TMAX; i += 128) (&pout[0][0])[i] = -1;
    __syncthreads();
    if (L < BB) {
        int cur = L, pos = mylen - 1;
        for (int tt = T - 1; tt >= 0; --tt) {
            unsigned short h = hist[tt][cur];
            int tk2 = (h >> 8) - 1;
            if (tk2 >= 0) pout[L][pos--] = (signed char)tk2;
            cur = h & 255;
        }
        if (mylen == 0 && cur > 0) pout[L][0] = (signed char)(-(cur + 2));  // guard
    }
    __syncthreads();
    for (int e = L; e < BB * T; e += 128) {
        int j = e / T, p = e - j * T;
        out[BB + e] = (float)pout[j][p];
    }
}

extern "C" void kernel_launch(void* const* d_in, const int* in_sizes, int n_in,
                              void* d_out, int out_size, void* d_ws, size_t ws_size,
                              hipStream_t stream) {
    const float* logits = (const float*)d_in[0];
    const int* blank_p = (const int*)d_in[2];
    int T = in_sizes[0] / VV;   // 200
    float* tkbuf = (float*)d_ws;                               // T*FS floats

    size_t ff_off = ((size_t)T * FS * 4 + 255) & ~(size_t)255; // frame flags
    unsigned int* fflags = (unsigned int*)((char*)d_ws + ff_off);

    fused_kernel<<<dim3(1 + T), dim3(128), 0, stream>>>(
        logits, blank_p, (float*)d_out, T, tkbuf, fflags);
}

// Round 14
// 528.198 us; speedup vs baseline: 1.0172x; 1.0172x over previous
//
#include <hip/hip_runtime.h>
#include <math.h>

// CTC prefix beam search — fused single dispatch.
//  blocks 1..T: per-frame log-softmax + stable top-10 + 32-entry symbol->logp
//               LUT (sentinel=+inf if not in top-10) -> d_ws.
//  block 0 (2 waves): one candidate per lane (110); lanes 110-119 rank-shadow
//  the g1 keys. Winners prefetch next frame's lut[nlast] at COMMIT time.
//  Bulk LDS preload after a single wait-all (R13's JIT staging regressed).
//  2 barriers/step.

#define BB 10
#define KK 10
#define VV 29
#define TMAX 256
#define FS 56                 // floats per frame record
#define NEGF (-1e30f)
#define DUPF (-2e30f)
#define MAGICF 0x5CA7F00Du
#define SENTB 0x7F800000      // +inf bits: "symbol not in top-10"

__device__ __forceinline__ float lae(float a, float b) {
    float m = fmaxf(a, b);
    return m + log1pf(expf(fminf(a, b) - m));
}
__device__ __forceinline__ unsigned int ordf(float f) {
    unsigned int u = __float_as_uint(f);
    return (u & 0x80000000u) ? ~u : (u | 0x80000000u);
}

// frame record (56 floats): [0..19] (sym_bits,p)*10 ; [20] blank_slot_bits ;
// [21] p_blank ; [22..23] pad ; [24..55] lut[32]
__device__ __forceinline__ void topk_frame(const float* __restrict__ logits,
                                           int blank, int t, float* __restrict__ o,
                                           int L) {
    float lp = (L < VV) ? logits[t * VV + L] : -INFINITY;
    float mx = lp;
    #pragma unroll
    for (int off = 32; off >= 1; off >>= 1) mx = fmaxf(mx, __shfl_xor(mx, off));
    float sm = (L < VV) ? expf(lp - mx) : 0.f;
    #pragma unroll
    for (int off = 32; off >= 1; off >>= 1) sm += __shfl_xor(sm, off);
    float lz = mx + logf(sm);
    int arank = 0;
    #pragma unroll
    for (int u = 0; u < VV; ++u) {
        float lu = __shfl(lp, u);
        arank += (lu > lp) || (lu == lp && u < L);   // tie -> lower index
    }
    bool win = (L < VV) && (arank < KK);
    if (win) { o[2 * arank] = __int_as_float(L); o[2 * arank + 1] = lp - lz; }
    if (L < 32) o[24 + L] = win ? (lp - lz) : __int_as_float(SENTB);
    unsigned long long bm = __ballot(win && (L == blank));
    if (bm) { if (L == blank) { o[20] = __int_as_float(arank); o[21] = lp - lz; } }
    else    { if (L == 0)     { o[20] = __int_as_float(-1);    o[21] = 0.f;     } }
}

__global__ __launch_bounds__(128) void fused_kernel(
        const float* __restrict__ logits, const int* __restrict__ blank_p,
        float* __restrict__ out, int T, float* __restrict__ tkbuf,
        unsigned int* fflags) {

    const int L = threadIdx.x;

    if (blockIdx.x != 0) {
        const int t = blockIdx.x - 1;
        if (L < 64) topk_frame(logits, blank_p[0], t, tkbuf + t * FS, L);
        __syncthreads();
        if (L == 0)
            __hip_atomic_store(&fflags[t], MAGICF, __ATOMIC_RELEASE,
                               __HIP_MEMORY_SCOPE_AGENT);
        return;
    }

    // ========================= scan block (2 waves) =========================
    __shared__ __align__(16) float tkl[TMAX * FS];
    __shared__ __align__(16) float bsrow[16][8];  // {pb,pnb,f2,len, ppb,ppnb,pkl,_}
    __shared__ __align__(16) int   dupsig[12];    // (last+16) | (par+1)<<8
    __shared__ __align__(16) unsigned long long kbuf[128];
    __shared__ __align__(16) float4 aux4[12];     // {pay_pb,pay_pnb,nlast+16,_}
    __shared__ unsigned short hist[TMAX][BB];
    __shared__ signed char pout[BB][TMAX];

    if (L < BB) {
        int last0 = (L == 0) ? -1 : -(L + 2);     // empty=slot0, sentinels 1..9
        int par0  = (L == 0) ? -1 : 0;
        int f2 = (last0 + 16) | ((par0 + 1) << 8) | ((-1 + 16) << 16);
        *(float4*)&bsrow[L][0] = make_float4((L == 0) ? 0.f : NEGF, NEGF,
                                             __int_as_float(f2), __int_as_float(0));
        // parent payload = empty beam; own pkl = sentinel (no valid last at t=0)
        *(float4*)&bsrow[L][4] = make_float4(0.f, NEGF, __int_as_float(SENTB), 0.f);
        dupsig[L] = f2 & 0xFFFF;
    } else if (L < 12) dupsig[L] = 0;

    // wait for all frames' top-k (wave0 polls; wave1 parks at the barrier)
    if (L < 64) {
        for (;;) {
            bool ok = true;
            for (int base = 0; base < T; base += 64) {
                int idx = base + L;
                unsigned f = (idx < T)
                    ? __hip_atomic_load(&fflags[idx], __ATOMIC_RELAXED,
                                        __HIP_MEMORY_SCOPE_AGENT)
                    : MAGICF;
                ok = ok && (f == MAGICF);
            }
            if (__all(ok)) break;
        }
    }
    __syncthreads();
    __builtin_amdgcn_fence(__ATOMIC_ACQUIRE, "agent");

    {   // preload all frames' records into LDS (bulk, both waves)
        int n4 = (T * FS) >> 2;
        const float4* g4 = (const float4*)tkbuf;
        float4* l4 = (float4*)tkl;
        for (int i = L; i < n4; i += 128) l4[i] = g4[i];
    }
    __syncthreads();

    // roles: L<10 real g1 (c=L); 10..109 g2 (c=L); 110..119 rank-shadow; rest idle
    const int c = L;
    const bool active = c < BB + BB * KK;         // 110
    const bool isg1 = c < BB;
    const bool isshadow = (L >= 110 && L < 120);
    const int b = isg1 ? c : (c - 10) / 10;
    const int k = isg1 ? 0 : (c - 10) % 10;
    const int ofs = isg1 ? 20 : 2 * k;            // uniform per-lane frame offset
    const int blank = blank_p[0];

    float2 fpr = *(const float2*)&tkl[ofs];       // frame t=0 data for this lane

    for (int t = 0; t < T; ++t) {
        // ---- P1: candidate scores (state reads ordered by prev end barrier)
        float tot = -INFINITY, pay_pb = NEGF, pay_pnb = NEGF;
        int nlen = 0, nlast = 0, xsl = -1, tok = -1;

        if (active) {
            float4 rowA = *(const float4*)&bsrow[b][0];
            int f2 = __float_as_int(rowA.z);
            int last_b = (f2 & 255) - 16;
            if (isg1) {
                float4 rowB = *(const float4*)&bsrow[b][4];   // {ppb,ppnb,pkl,_}
                int par_b  = ((f2 >> 8) & 255) - 1;
                int last_p = ((f2 >> 16) & 255) - 16;
                nlen = __float_as_int(rowA.w);
                nlast = last_b; xsl = par_b; tok = -1;
                int bk = __float_as_int(fpr.x);               // blank slot or -1
                float pbl = fpr.y;
                float pkl = rowB.z;
                if (bk >= 0) pay_pb = lae(rowA.x + pbl, rowA.y + pbl);
                if (__float_as_int(rowB.z) != SENTB) {
                    float a = rowA.y + pkl;                   // g1 member (lower idx)
                    if (par_b >= 0) {
                        float e = (last_b == last_p) ? (rowB.x + pkl)
                                   : lae(rowB.x + pkl, rowB.y + pkl);
                        float mxx = fmaxf(a, e);
                        pay_pnb = mxx + logf(expf(a - mxx) + expf(e - mxx));
                    } else pay_pnb = a;
                }
                tot = lae(pay_pb, pay_pnb);
            } else {
                int s = __float_as_int(fpr.x); float p = fpr.y;
                nlen = __float_as_int(rowA.w) + 1;
                nlast = s; xsl = b; tok = s;
                int4 dg0 = *(const int4*)&dupsig[0];
                int4 dg1 = *(const int4*)&dupsig[4];
                int2 dg2 = *(const int2*)&dupsig[8];
                int sig[BB] = {dg0.x, dg0.y, dg0.z, dg0.w,
                               dg1.x, dg1.y, dg1.z, dg1.w, dg2.x, dg2.y};
                int target = ((b + 1) << 8) | (s + 16);
                bool dup = false;
                #pragma unroll
                for (int i = 0; i < BB; ++i) dup = dup || (sig[i] == target);
                float v;
                if (s == blank)        v = NEGF;
                else if (s == last_b)  v = rowA.x + p;
                else                   v = lae(rowA.x + p, rowA.y + p);
                pay_pnb = v;
                tot = dup ? DUPF : v;        // lae(NEGF,v) == v bitwise in f32
            }
        }

        unsigned long long key =
            (((unsigned long long)ordf(tot)) << 32) | (unsigned)(127 - c);
        if (active) kbuf[c] = key;
        if (isg1)   aux4[c] = make_float4(pay_pb, pay_pnb,
                                          __int_as_float(nlast + 16), 0.f);
        __syncthreads();                                   // B1: keys+aux visible

        // shadow lanes adopt the g1 key they will rank (issued first post-B1)
        if (isshadow) key = kbuf[L - 110];

        // prefetch next frame's per-lane float2 (hidden under rank)
        int tn = (t + 1 < T) ? (t + 1) : t;
        const float* tkn = &tkl[tn * FS];
        fpr = *(const float2*)&tkn[ofs];

        // ---- exact rank (value desc, index asc) vs all 110 keys (wave-uniform)
        int r = 0;
        const ulonglong2* k2 = (const ulonglong2*)kbuf;
        #pragma unroll
        for (int q = 0; q < 55; ++q) {
            ulonglong2 w = k2[q];
            r += (w.x > key) + (w.y > key);
        }

        // parent new-slot via intra-wave shuffle:
        // wave0 sources = real g1 lanes 0-9; wave1 sources = shadow 46-55 (rel).
        int g1r_val = ((isg1 || isshadow) && r < BB) ? r : -1;
        int xs = (xsl < 0) ? 0 : xsl;
        int src = (L < 64) ? xs : (46 + xs);
        int g1r_sh = __shfl(g1r_val, src);

        // ---- full commit (winners only; ranks unique)
        if (active && r < BB) {
            float4 ax = aux4[xs];          // parent payload (pre-B1 publish)
            int npar, plast16; float ppb, ppnb;
            if (xsl >= 0) {
                npar = g1r_sh; plast16 = __float_as_int(ax.z);
                ppb = ax.x; ppnb = ax.y;
            } else { npar = -1; plast16 = 15; ppb = 0.f; ppnb = NEGF; }
            // prefetch next frame's lut[nlast] for own g1 next step
            int li = ((unsigned)nlast < VV) ? nlast : 29;   // 29..31 = sentinel
            float npkl = tkn[24 + li];
            int f2n = (nlast + 16) | ((npar + 1) << 8) | (plast16 << 16);
            *(float4*)&bsrow[r][0] = make_float4(isg1 ? pay_pb : NEGF, pay_pnb,
                                                 __int_as_float(f2n),
                                                 __int_as_float(nlen));
            *(float4*)&bsrow[r][4] = make_float4(ppb, ppnb, npkl, 0.f);
            dupsig[r] = f2n & 0xFFFF;
            hist[t][r] = (unsigned short)(b | ((tok + 1) << 8));
        }
        __syncthreads();                                   // B2: state committed
    }

    // ---- outputs: [scores(B) | prefixes(B*T) | lengths(B)] as f32
    int mylen = 0;
    if (L < BB) {
        float4 rj = *(const float4*)&bsrow[L][0];
        mylen = __float_as_int(rj.w);
        out[L] = lae(rj.x, rj.y);
        out[BB + BB * T + L] = (float)mylen;
    }
    for (int i = L; i < BB * TMAX; i += 128) (&pout[0][0])[i] = -1;
    __syncthreads();
    if (L < BB) {
        int cur = L, pos = mylen - 1;
        for (int tt = T - 1; tt >= 0; --tt) {
            unsigned short h = hist[tt][cur];
            int tk2 = (h >> 8) - 1;
            if (tk2 >= 0) pout[L][pos--] = (signed char)tk2;
            cur = h & 255;
        }
        if (mylen == 0 && cur > 0) pout[L][0] = (signed char)(-(cur + 2));  // guard
    }
    __syncthreads();
    for (int e = L; e < BB * T; e += 128) {
        int j = e / T, p = e - j * T;
        out[BB + e] = (float)pout[j][p];
    }
}

extern "C" void kernel_launch(void* const* d_in, const int* in_sizes, int n_in,
                              void* d_out, int out_size, void* d_ws, size_t ws_size,
                              hipStream_t stream) {
    const float* logits = (const float*)d_in[0];
    const int* blank_p = (const int*)d_in[2];
    int T = in_sizes[0] / VV;   // 200
    float* tkbuf = (float*)d_ws;                               // T*FS floats

    size_t ff_off = ((size_t)T * FS * 4 + 255) & ~(size_t)255; // frame flags
    unsigned int* fflags = (unsigned int*)((char*)d_ws + ff_off);

    fused_kernel<<<dim3(1 + T), dim3(128), 0, stream>>>(
        logits, blank_p, (float*)d_out, T, tkbuf, fflags);
}